// Round 15
// baseline (305.034 us; speedup 1.0000x reference)
//
#include <hip/hip_runtime.h>
#include <hip/hip_bf16.h>

#define NN 50000
#define NE 800000
#define DD 128
#define NB 196             // ceil(NN/256)
#define NCH 8              // source chunks
#define CHSZ 6250          // NN / NCH
#define NC2 (NN * NCH)     // per-(node,chunk) bins = 400000
#define NSB 391            // ceil(NC2/1024)
#define PH (64 * NB)       // degree-bucket histogram size = 12544
#define FS 2048            // edges per slice (hist + fill partitioning)
#define NSL 391            // ceil(NE/FS)
#define HHB (NSL * 8)      // hist blocks, XCD-partitioned = 3128
#define QB 3125            // quant-cast blocks (NN/16)
#define WB 192             // wtcast blocks
#define LN_EPS 1e-5f

typedef __bf16 bf16x8 __attribute__((ext_vector_type(8)));
typedef float f32x4 __attribute__((ext_vector_type(4)));

__device__ inline ushort f2bf_bits(float f) {
    union { __hip_bfloat16 h; ushort u; } c;
    c.h = __float2bfloat16(f);
    return c.u;
}

__device__ inline void accum_q(float* acc, uint2 qv, float ww) {
    uint lo = qv.x, hi = qv.y;
    acc[0] = fmaf(ww, (float)(char)(lo), acc[0]);
    acc[1] = fmaf(ww, (float)(char)(lo >> 8), acc[1]);
    acc[2] = fmaf(ww, (float)(char)(lo >> 16), acc[2]);
    acc[3] = fmaf(ww, (float)(char)(lo >> 24), acc[3]);
    acc[4] = fmaf(ww, (float)(char)(hi), acc[4]);
    acc[5] = fmaf(ww, (float)(char)(hi >> 8), acc[5]);
    acc[6] = fmaf(ww, (float)(char)(hi >> 16), acc[6]);
    acc[7] = fmaf(ww, (float)(char)(hi >> 24), acc[7]);
}

// ---- fused: XCD-partitioned hist (ballot-compacted) + int8 row-quant cast + Wt cast ----
__global__ void hist_cast_kernel(const int* __restrict__ src, const int* __restrict__ dst,
                                 int* __restrict__ counts2, const float* __restrict__ x,
                                 uint2* __restrict__ qf0, float* __restrict__ sc0,
                                 const float* __restrict__ W, ushort* __restrict__ Wt) {
    __shared__ int qbin[4][512];
    int b = blockIdx.x;
    if (b < HHB) {
        int slice = b >> 3;
        int r = b & 7;
        int base = slice * FS;
        int w = threadIdx.x >> 6, lane = threadIdx.x & 63;
        int qn = 0;
        // scan phase: compact matching edges' bins into per-wave LDS queue
#pragma unroll
        for (int it = 0; it < 8; ++it) {
            int e = base + it * 256 + threadIdx.x;
            bool match = false;
            int bin = 0;
            if (e < NE) {
                int d = dst[e];
                if (d / CHSZ == r) {
                    match = true;
                    bin = d * NCH + src[e] / CHSZ;
                }
            }
            unsigned long long mask = __ballot(match);
            int rank = __popcll(mask & ((1ull << lane) - 1ull));
            if (match) qbin[w][qn + rank] = bin;
            qn += __popcll(mask);
        }
        // dense phase: all lanes active
        for (int k = lane; k < qn; k += 64) atomicAdd(&counts2[qbin[w][k]], 1);
    } else if (b < HHB + QB) {
        // per-node int8 quantization: 16 lanes x 8 floats = one 128-elem row
        int bb = b - HHB;
        int group = threadIdx.x >> 4, t = threadIdx.x & 15;
        int node = bb * 16 + group;  // 3125*16 = 50000 exact
        const float4* xr = (const float4*)(x + (size_t)node * DD + t * 8);
        float4 v0 = xr[0], v1 = xr[1];
        float vals[8] = {v0.x, v0.y, v0.z, v0.w, v1.x, v1.y, v1.z, v1.w};
        float am = 0.f;
#pragma unroll
        for (int i = 0; i < 8; ++i) am = fmaxf(am, fabsf(vals[i]));
#pragma unroll
        for (int off = 1; off <= 8; off <<= 1) am = fmaxf(am, __shfl_xor(am, off, 64));
        float inv = 127.f / fmaxf(am, 1e-20f);
        uint lo = 0, hi = 0;
#pragma unroll
        for (int i = 0; i < 4; ++i) {
            int q = __float2int_rn(vals[i] * inv);
            lo |= ((uint)(q & 0xff)) << (8 * i);
        }
#pragma unroll
        for (int i = 0; i < 4; ++i) {
            int q = __float2int_rn(vals[4 + i] * inv);
            hi |= ((uint)(q & 0xff)) << (8 * i);
        }
        uint2 pk; pk.x = lo; pk.y = hi;
        qf0[node * 16 + t] = pk;
        if (t == 0) sc0[node] = am / 127.f;
    } else {
        int i = (b - HHB - QB) * 256 + threadIdx.x;  // 3*128*128 = 49152
        int l = i >> 14, k = (i >> 7) & 127, n = i & 127;
        Wt[l * 16384 + n * 128 + k] = f2bf_bits(W[i]);
    }
}

// level-0 scan over NC2 elements, 1024 threads/block, in-place; emits block sums
__global__ __launch_bounds__(1024) void scan1024_blocks(int* __restrict__ data,
                                                        int* __restrict__ bsums) {
    __shared__ int ws[16];
    int gid = blockIdx.x * 1024 + threadIdx.x;
    int lane = threadIdx.x & 63, wid = threadIdx.x >> 6;
    int v = (gid < NC2) ? data[gid] : 0;
    int x = v;
#pragma unroll
    for (int off = 1; off < 64; off <<= 1) {
        int t = __shfl_up(x, off, 64);
        if (lane >= off) x += t;
    }
    if (lane == 63) ws[wid] = x;
    __syncthreads();
    if (threadIdx.x == 0) {
        int run = 0;
        for (int i = 0; i < 16; ++i) { int t = ws[i]; ws[i] = run; run += t; }
        bsums[blockIdx.x] = run;
    }
    __syncthreads();
    if (gid < NC2) data[gid] = x - v + ws[wid];
}

// level-1: single block scans the 391 block sums
__global__ __launch_bounds__(1024) void scan_sums1024(int* __restrict__ bsums, int nb) {
    __shared__ int ws[16];
    int tid = threadIdx.x;
    int lane = tid & 63, wid = tid >> 6;
    int v = (tid < nb) ? bsums[tid] : 0;
    int x = v;
#pragma unroll
    for (int off = 1; off < 64; off <<= 1) {
        int t = __shfl_up(x, off, 64);
        if (lane >= off) x += t;
    }
    if (lane == 63) ws[wid] = x;
    __syncthreads();
    if (tid == 0) {
        int run = 0;
        for (int i = 0; i < 16; ++i) { int t = ws[i]; ws[i] = run; run += t; }
    }
    __syncthreads();
    if (tid < nb) bsums[tid] = x - v + ws[wid];
}

// absolute cursors, row_ptr, degree, dinv + degree histogram (bins REVERSED ->
// longest-job-first block scheduling for the layer kernels; numerics unaffected)
__global__ void finalize_kernel(const int* __restrict__ excl2, const int* __restrict__ bsums,
                                int* __restrict__ row_ptr, int* __restrict__ next_pos2,
                                float* __restrict__ dinv, int* __restrict__ degarr,
                                int* __restrict__ bh) {
    __shared__ int lh[64];
    if (threadIdx.x < 64) lh[threadIdx.x] = 0;
    __syncthreads();
    int d = blockIdx.x * 256 + threadIdx.x;
    if (d < NN) {
        int base = d * NCH;
        int p0 = excl2[base] + bsums[base >> 10];
#pragma unroll
        for (int c = 0; c < NCH; ++c) {
            int idx = base + c;
            next_pos2[idx] = excl2[idx] + bsums[idx >> 10];
        }
        int nxt = (d == NN - 1) ? NE : excl2[base + NCH] + bsums[(base + NCH) >> 10];
        int deg = nxt - p0;
        row_ptr[d] = p0;
        dinv[d] = rsqrtf((float)deg + 1.0f);
        degarr[d] = deg;
        atomicAdd(&lh[63 - min(deg, 63)], 1);
    }
    __syncthreads();
    if (threadIdx.x < 64) bh[threadIdx.x * NB + blockIdx.x] = lh[threadIdx.x];
    if (blockIdx.x == 0 && threadIdx.x == 0) row_ptr[NN] = NE;
}

__global__ __launch_bounds__(1024) void permscan_kernel(int* __restrict__ bh) {
    __shared__ int wsum[16];
    const int CH = 13;  // 1024*13 = 13312 >= 12544
    int tid = threadIdx.x;
    int base = tid * CH;
    int vals[CH];
    int s = 0;
#pragma unroll
    for (int i = 0; i < CH; ++i) {
        int idx = base + i;
        int v = (idx < PH) ? bh[idx] : 0;
        vals[i] = s;
        s += v;
    }
    int lane = tid & 63, wid = tid >> 6;
    int x = s;
#pragma unroll
    for (int off = 1; off < 64; off <<= 1) {
        int t = __shfl_up(x, off, 64);
        if (lane >= off) x += t;
    }
    if (lane == 63) wsum[wid] = x;
    __syncthreads();
    if (tid == 0) {
        int run = 0;
        for (int i = 0; i < 16; ++i) { int t = wsum[i]; wsum[i] = run; run += t; }
    }
    __syncthreads();
    int texcl = x - s + wsum[wid];
#pragma unroll
    for (int i = 0; i < CH; ++i) {
        int idx = base + i;
        if (idx < PH) bh[idx] = texcl + vals[i];
    }
}

// merged: blocks [0,NB) = degree-bucket permscatter (reversed bins = descending degree);
// blocks [NB,..) = XCD-partitioned fill with ballot compaction into per-wave LDS queue.
__global__ void scatter_fill_kernel(const int* __restrict__ degarr, const int* __restrict__ bh,
                                    int* __restrict__ perm, const int* __restrict__ src,
                                    const int* __restrict__ dst, int* __restrict__ next_pos2,
                                    const float* __restrict__ dinv, int2* __restrict__ edge2) {
    if (blockIdx.x < NB) {
        __shared__ int lh[64];
        __shared__ int lbase[64];
        if (threadIdx.x < 64) {
            lh[threadIdx.x] = 0;
            lbase[threadIdx.x] = bh[threadIdx.x * NB + blockIdx.x];
        }
        __syncthreads();
        int gid = blockIdx.x * 256 + threadIdx.x;
        if (gid < NN) {
            int b = 63 - min(degarr[gid], 63);
            int r = atomicAdd(&lh[b], 1);
            perm[lbase[b] + r] = gid;
        }
    } else {
        __shared__ int2 qsd[4][512];
        int bb = blockIdx.x - NB;
        int slice = bb >> 3;
        int r = bb & 7;
        int base = slice * FS;
        int w = threadIdx.x >> 6, lane = threadIdx.x & 63;
        int qn = 0;
#pragma unroll
        for (int it = 0; it < 8; ++it) {
            int e = base + it * 256 + threadIdx.x;
            bool match = false;
            int2 sd;
            if (e < NE) {
                int d = dst[e];
                if (d / CHSZ == r) {
                    match = true;
                    sd.x = src[e];
                    sd.y = d;
                }
            }
            unsigned long long mask = __ballot(match);
            int rank = __popcll(mask & ((1ull << lane) - 1ull));
            if (match) qsd[w][qn + rank] = sd;
            qn += __popcll(mask);
        }
        for (int k = lane; k < qn; k += 64) {
            int s = qsd[w][k].x, d = qsd[w][k].y;
            int pos = atomicAdd(&next_pos2[d * NCH + s / CHSZ], 1);
            int2 o;
            o.x = s;
            o.y = __float_as_int(dinv[s] * dinv[d]);
            edge2[pos] = o;
        }
    }
}

// ---------------- fused per-layer: int8 gather-aggregate + MFMA GEMM + bias+LN+ReLU+res ----
// int8 table (128B row = 2 lines), x8 gather pipeline, perm now descending-degree
// (longest-job-first -> lighter grid tail).
template <bool RES, bool FINAL>
__global__ __launch_bounds__(256) void layer_kernel(
    const uint2* __restrict__ qin, const float* __restrict__ scin,
    const ushort* __restrict__ fin, const int* __restrict__ row_ptr,
    const int2* __restrict__ edge2, const int* __restrict__ perm,
    const float* __restrict__ dinv, const ushort* __restrict__ Wt,
    const float* __restrict__ bias, const float* __restrict__ gamma,
    const float* __restrict__ beta, ushort* __restrict__ fout, char* __restrict__ qfout,
    float* __restrict__ scout, float* __restrict__ out) {
    __shared__ uint4 sA[16 * 17];
    __shared__ int sNode[16];
    __shared__ float sLN1[4][16], sLN2[4][16];
    __shared__ float sMX[4][16];

    int w = threadIdx.x >> 6, lane = threadIdx.x & 63;
    int g = lane >> 4, t = lane & 15;
    int arow = w * 4 + g;
    int slot = blockIdx.x * 16 + arow;  // grid 3125*16 = 50000 exact
    int node = perm[slot];
    if (t == 0) sNode[arow] = node;

    // ---- phase 1: int8 gather-aggregate (16 lanes x 8B per node row), x8 pipelined ----
    {
        int beg = row_ptr[node], end = row_ptr[node + 1];
        float acc[8] = {};
        int e = beg;
        for (; e + 8 <= end; e += 8) {
            int2 a[8];
            uint2 qv[8];
            float sc[8];
#pragma unroll
            for (int j = 0; j < 8; ++j) a[j] = edge2[e + j];
#pragma unroll
            for (int j = 0; j < 8; ++j) {
                qv[j] = qin[a[j].x * 16 + t];
                sc[j] = scin[a[j].x];
            }
#pragma unroll
            for (int j = 0; j < 8; ++j) accum_q(acc, qv[j], __int_as_float(a[j].y) * sc[j]);
        }
        for (; e + 4 <= end; e += 4) {
            int2 a[4];
            uint2 qv[4];
            float sc[4];
#pragma unroll
            for (int j = 0; j < 4; ++j) a[j] = edge2[e + j];
#pragma unroll
            for (int j = 0; j < 4; ++j) {
                qv[j] = qin[a[j].x * 16 + t];
                sc[j] = scin[a[j].x];
            }
#pragma unroll
            for (int j = 0; j < 4; ++j) accum_q(acc, qv[j], __int_as_float(a[j].y) * sc[j]);
        }
        for (; e < end; ++e) {
            int2 a = edge2[e];
            uint2 qv = qin[a.x * 16 + t];
            accum_q(acc, qv, __int_as_float(a.y) * scin[a.x]);
        }
        {
            float di = dinv[node];
            uint2 qv = qin[node * 16 + t];
            accum_q(acc, qv, di * di * scin[node]);
        }
        union { ushort us[8]; uint4 u; } pk;
#pragma unroll
        for (int i = 0; i < 8; ++i) pk.us[i] = f2bf_bits(acc[i]);
        sA[arow * 17 + t] = pk.u;
    }
    __syncthreads();

    // ---- phase 2: MFMA 16x128 tile; wave w owns col-tiles 2w, 2w+1 ----
    int q = lane >> 4, m = lane & 15;
    f32x4 c0 = (f32x4){0.f, 0.f, 0.f, 0.f};
    f32x4 c1 = (f32x4){0.f, 0.f, 0.f, 0.f};
    int n0 = 16 * (2 * w), n1 = 16 * (2 * w + 1);
#pragma unroll
    for (int kk = 0; kk < 4; ++kk) {
        bf16x8 af = *(const bf16x8*)&sA[m * 17 + kk * 4 + q];
        bf16x8 b0 = *(const bf16x8*)(Wt + (n0 + m) * DD + kk * 32 + q * 8);
        bf16x8 b1 = *(const bf16x8*)(Wt + (n1 + m) * DD + kk * 32 + q * 8);
        c0 = __builtin_amdgcn_mfma_f32_16x16x32_bf16(af, b0, c0, 0, 0, 0);
        c1 = __builtin_amdgcn_mfma_f32_16x16x32_bf16(af, b1, c1, 0, 0, 0);
    }

    // ---- epilogue: bias + LN + ReLU + residual; non-final layers also emit int8 ----
    float bb0 = bias[n0 + m], bb1 = bias[n1 + m];
    float s1[4], s2[4];
#pragma unroll
    for (int r = 0; r < 4; ++r) {
        float v0 = c0[r] + bb0, v1 = c1[r] + bb1;
        c0[r] = v0; c1[r] = v1;
        s1[r] = v0 + v1;
        s2[r] = v0 * v0 + v1 * v1;
    }
#pragma unroll
    for (int off = 1; off <= 8; off <<= 1) {
#pragma unroll
        for (int r = 0; r < 4; ++r) {
            s1[r] += __shfl_xor(s1[r], off, 64);
            s2[r] += __shfl_xor(s2[r], off, 64);
        }
    }
    if (m == 0) {
#pragma unroll
        for (int r = 0; r < 4; ++r) {
            sLN1[w][q * 4 + r] = s1[r];
            sLN2[w][q * 4 + r] = s2[r];
        }
    }
    __syncthreads();
    float ga0 = gamma[n0 + m], ga1 = gamma[n1 + m];
    float be0 = beta[n0 + m], be1 = beta[n1 + m];
    float o0v[4], o1v[4], rmax[4];
#pragma unroll
    for (int r = 0; r < 4; ++r) {
        int row = q * 4 + r;
        float S1 = sLN1[0][row] + sLN1[1][row] + sLN1[2][row] + sLN1[3][row];
        float S2 = sLN2[0][row] + sLN2[1][row] + sLN2[2][row] + sLN2[3][row];
        float mu = S1 * (1.f / 128.f);
        float var = S2 * (1.f / 128.f) - mu * mu;
        float rstd = rsqrtf(var + LN_EPS);
        int nd = sNode[row];
        size_t rb = (size_t)nd * DD;
        float o0 = fmaxf((c0[r] - mu) * rstd * ga0 + be0, 0.f);
        float o1 = fmaxf((c1[r] - mu) * rstd * ga1 + be1, 0.f);
        if (RES) {
            o0 += __uint_as_float(((uint)fin[rb + n0 + m]) << 16);
            o1 += __uint_as_float(((uint)fin[rb + n1 + m]) << 16);
        }
        if (FINAL) {
            out[rb + n0 + m] = o0;
            out[rb + n1 + m] = o1;
        } else {
            fout[rb + n0 + m] = f2bf_bits(o0);
            fout[rb + n1 + m] = f2bf_bits(o1);
            o0v[r] = o0; o1v[r] = o1;
            rmax[r] = fmaxf(o0, o1);  // o >= 0
        }
    }
    if (!FINAL) {
#pragma unroll
        for (int off = 1; off <= 8; off <<= 1) {
#pragma unroll
            for (int r = 0; r < 4; ++r) rmax[r] = fmaxf(rmax[r], __shfl_xor(rmax[r], off, 64));
        }
        if (m == 0) {
#pragma unroll
            for (int r = 0; r < 4; ++r) sMX[w][q * 4 + r] = rmax[r];
        }
        __syncthreads();
#pragma unroll
        for (int r = 0; r < 4; ++r) {
            int row = q * 4 + r;
            float M = fmaxf(fmaxf(sMX[0][row], sMX[1][row]), fmaxf(sMX[2][row], sMX[3][row]));
            float inv = 127.f / fmaxf(M, 1e-20f);
            int nd = sNode[row];
            if (w == 0 && m == 0) scout[nd] = M / 127.f;
            int q0 = min(__float2int_rn(o0v[r] * inv), 127);
            int q1 = min(__float2int_rn(o1v[r] * inv), 127);
            qfout[(size_t)nd * DD + n0 + m] = (char)q0;
            qfout[(size_t)nd * DD + n1 + m] = (char)q1;
        }
    }
}

// ---------------- launch ----------------

extern "C" void kernel_launch(void* const* d_in, const int* in_sizes, int n_in,
                              void* d_out, int out_size, void* d_ws, size_t ws_size,
                              hipStream_t stream) {
    const float* x = (const float*)d_in[0];
    const int* edge = (const int*)d_in[1];
    const float* Ws = (const float*)d_in[2];
    const float* bs = (const float*)d_in[3];
    const float* gs = (const float*)d_in[4];
    const float* bes = (const float*)d_in[5];
    float* out = (float*)d_out;
    const int* src = edge;
    const int* dst = edge + NE;

    char* p = (char*)d_ws;
    int* counts2 = (int*)p;     p += (size_t)NC2 * 4;     // scanned in place
    int* bsums = (int*)p;       p += 1024 * 4;
    int* row_ptr = (int*)p;     p += (size_t)(NN + 4) * 4;
    int* next_pos2 = (int*)p;   p += (size_t)NC2 * 4;
    float* dinv = (float*)p;    p += (size_t)NN * 4;
    int* degarr = (int*)p;      p += (size_t)NN * 4;
    int* bh = (int*)p;          p += (size_t)PH * 4;
    int* perm = (int*)p;        p += (size_t)NN * 4;
    int2* edge2 = (int2*)p;     p += (size_t)NE * 8;
    ushort* fb0 = (ushort*)p;   p += (size_t)NN * DD * 2;   // bf16 residual chain
    ushort* fb1 = (ushort*)p;   p += (size_t)NN * DD * 2;
    char* qf0 = (char*)p;       p += (size_t)NN * DD;       // int8 gather tables
    char* qf1 = (char*)p;       p += (size_t)NN * DD;
    float* sc0 = (float*)p;     p += (size_t)NN * 4;        // per-row scales
    float* sc1 = (float*)p;     p += (size_t)NN * 4;
    ushort* Wt = (ushort*)p;    p += (size_t)3 * DD * DD * 2;

    hipMemsetAsync(counts2, 0, (size_t)NC2 * 4, stream);
    hist_cast_kernel<<<HHB + QB + WB, 256, 0, stream>>>(src, dst, counts2, x, (uint2*)qf0,
                                                        sc0, Ws, Wt);
    scan1024_blocks<<<NSB, 1024, 0, stream>>>(counts2, bsums);
    scan_sums1024<<<1, 1024, 0, stream>>>(bsums, NSB);
    finalize_kernel<<<NB, 256, 0, stream>>>(counts2, bsums, row_ptr, next_pos2, dinv, degarr,
                                            bh);
    permscan_kernel<<<1, 1024, 0, stream>>>(bh);
    scatter_fill_kernel<<<NB + NSL * 8, 256, 0, stream>>>(degarr, bh, perm, src, dst,
                                                          next_pos2, dinv, edge2);

    int lg = NN / 16;  // 3125
    layer_kernel<false, false><<<lg, 256, 0, stream>>>(
        (const uint2*)qf0, sc0, fb0, row_ptr, edge2, perm, dinv, Wt, bs, gs, bes,
        fb1, qf1, sc1, out);
    layer_kernel<true, false><<<lg, 256, 0, stream>>>(
        (const uint2*)qf1, sc1, fb1, row_ptr, edge2, perm, dinv, Wt + 16384, bs + DD, gs + DD,
        bes + DD, fb0, qf0, sc0, out);
    layer_kernel<true, true><<<lg, 256, 0, stream>>>(
        (const uint2*)qf0, sc0, fb0, row_ptr, edge2, perm, dinv, Wt + 32768, bs + 2 * DD,
        gs + 2 * DD, bes + 2 * DD, fb1, qf1, sc1, out);
}

// Round 16
// 285.036 us; speedup vs baseline: 1.0702x; 1.0702x over previous
//
#include <hip/hip_runtime.h>
#include <hip/hip_bf16.h>

#define NN 50000
#define NE 800000
#define DD 128
#define NB 196             // ceil(NN/256)
#define NCH 8              // source chunks
#define CHSZ 6250          // NN / NCH
#define NC2 (NN * NCH)     // per-(node,chunk) bins = 400000
#define NSB 391            // ceil(NC2/1024)
#define PH (64 * NB)       // degree-bucket histogram size = 12544
#define FS 2048            // edges per slice (hist + fill partitioning)
#define NSL 391            // ceil(NE/FS)
#define HHB (NSL * 8)      // hist blocks, XCD-partitioned = 3128
#define QB 3125            // quant-cast blocks (NN/16)
#define WB 192             // wtcast blocks
#define LN_EPS 1e-5f

typedef __bf16 bf16x8 __attribute__((ext_vector_type(8)));
typedef float f32x4 __attribute__((ext_vector_type(4)));

__device__ inline ushort f2bf_bits(float f) {
    union { __hip_bfloat16 h; ushort u; } c;
    c.h = __float2bfloat16(f);
    return c.u;
}

__device__ inline void accum_q(float* acc, uint2 qv, float ww) {
    uint lo = qv.x, hi = qv.y;
    acc[0] = fmaf(ww, (float)(char)(lo), acc[0]);
    acc[1] = fmaf(ww, (float)(char)(lo >> 8), acc[1]);
    acc[2] = fmaf(ww, (float)(char)(lo >> 16), acc[2]);
    acc[3] = fmaf(ww, (float)(char)(lo >> 24), acc[3]);
    acc[4] = fmaf(ww, (float)(char)(hi), acc[4]);
    acc[5] = fmaf(ww, (float)(char)(hi >> 8), acc[5]);
    acc[6] = fmaf(ww, (float)(char)(hi >> 16), acc[6]);
    acc[7] = fmaf(ww, (float)(char)(hi >> 24), acc[7]);
}

// ---- fused: XCD-partitioned hist (rank-capturing) + int8 row-quant cast + Wt cast ----
// The hist atomicAdd's RETURN VALUE is the edge's within-bin rank; storing it makes the
// later fill a pure atomic-free scatter (kills 800k of the 1.6M preamble atomics).
__global__ void hist_cast_kernel(const int* __restrict__ src, const int* __restrict__ dst,
                                 int* __restrict__ counts2, int* __restrict__ rank,
                                 const float* __restrict__ x, uint2* __restrict__ qf0,
                                 float* __restrict__ sc0, const float* __restrict__ W,
                                 ushort* __restrict__ Wt) {
    int b = blockIdx.x;
    if (b < HHB) {
        int slice = b >> 3;
        int r = b & 7;
        int base = slice * FS;
#pragma unroll 2
        for (int i = threadIdx.x; i < FS; i += 256) {
            int e = base + i;
            if (e < NE) {
                int d = dst[e];
                if (d / CHSZ == r) {
                    int s = src[e];
                    rank[e] = atomicAdd(&counts2[d * NCH + s / CHSZ], 1);
                }
            }
        }
    } else if (b < HHB + QB) {
        // per-node int8 quantization: 16 lanes x 8 floats = one 128-elem row
        int bb = b - HHB;
        int group = threadIdx.x >> 4, t = threadIdx.x & 15;
        int node = bb * 16 + group;  // 3125*16 = 50000 exact
        const float4* xr = (const float4*)(x + (size_t)node * DD + t * 8);
        float4 v0 = xr[0], v1 = xr[1];
        float vals[8] = {v0.x, v0.y, v0.z, v0.w, v1.x, v1.y, v1.z, v1.w};
        float am = 0.f;
#pragma unroll
        for (int i = 0; i < 8; ++i) am = fmaxf(am, fabsf(vals[i]));
#pragma unroll
        for (int off = 1; off <= 8; off <<= 1) am = fmaxf(am, __shfl_xor(am, off, 64));
        float inv = 127.f / fmaxf(am, 1e-20f);
        uint lo = 0, hi = 0;
#pragma unroll
        for (int i = 0; i < 4; ++i) {
            int q = __float2int_rn(vals[i] * inv);
            lo |= ((uint)(q & 0xff)) << (8 * i);
        }
#pragma unroll
        for (int i = 0; i < 4; ++i) {
            int q = __float2int_rn(vals[4 + i] * inv);
            hi |= ((uint)(q & 0xff)) << (8 * i);
        }
        uint2 pk; pk.x = lo; pk.y = hi;
        qf0[node * 16 + t] = pk;
        if (t == 0) sc0[node] = am / 127.f;
    } else {
        int i = (b - HHB - QB) * 256 + threadIdx.x;  // 3*128*128 = 49152
        int l = i >> 14, k = (i >> 7) & 127, n = i & 127;
        Wt[l * 16384 + n * 128 + k] = f2bf_bits(W[i]);
    }
}

// level-0 scan over NC2 elements, 1024 threads/block, in-place; emits block sums
__global__ __launch_bounds__(1024) void scan1024_blocks(int* __restrict__ data,
                                                        int* __restrict__ bsums) {
    __shared__ int ws[16];
    int gid = blockIdx.x * 1024 + threadIdx.x;
    int lane = threadIdx.x & 63, wid = threadIdx.x >> 6;
    int v = (gid < NC2) ? data[gid] : 0;
    int x = v;
#pragma unroll
    for (int off = 1; off < 64; off <<= 1) {
        int t = __shfl_up(x, off, 64);
        if (lane >= off) x += t;
    }
    if (lane == 63) ws[wid] = x;
    __syncthreads();
    if (threadIdx.x == 0) {
        int run = 0;
        for (int i = 0; i < 16; ++i) { int t = ws[i]; ws[i] = run; run += t; }
        bsums[blockIdx.x] = run;
    }
    __syncthreads();
    if (gid < NC2) data[gid] = x - v + ws[wid];
}

// level-1: single block scans the 391 block sums
__global__ __launch_bounds__(1024) void scan_sums1024(int* __restrict__ bsums, int nb) {
    __shared__ int ws[16];
    int tid = threadIdx.x;
    int lane = tid & 63, wid = tid >> 6;
    int v = (tid < nb) ? bsums[tid] : 0;
    int x = v;
#pragma unroll
    for (int off = 1; off < 64; off <<= 1) {
        int t = __shfl_up(x, off, 64);
        if (lane >= off) x += t;
    }
    if (lane == 63) ws[wid] = x;
    __syncthreads();
    if (tid == 0) {
        int run = 0;
        for (int i = 0; i < 16; ++i) { int t = ws[i]; ws[i] = run; run += t; }
    }
    __syncthreads();
    if (tid < nb) bsums[tid] = x - v + ws[wid];
}

// row_ptr, degree, dinv + degree histogram (bins reversed -> longest-job-first layer
// scheduling; numerics unaffected). next_pos2 eliminated (rank trick).
__global__ void finalize_kernel(const int* __restrict__ excl2, const int* __restrict__ bsums,
                                int* __restrict__ row_ptr, float* __restrict__ dinv,
                                int* __restrict__ degarr, int* __restrict__ bh) {
    __shared__ int lh[64];
    if (threadIdx.x < 64) lh[threadIdx.x] = 0;
    __syncthreads();
    int d = blockIdx.x * 256 + threadIdx.x;
    if (d < NN) {
        int base = d * NCH;
        int p0 = excl2[base] + bsums[base >> 10];
        int nxt = (d == NN - 1) ? NE : excl2[base + NCH] + bsums[(base + NCH) >> 10];
        int deg = nxt - p0;
        row_ptr[d] = p0;
        dinv[d] = rsqrtf((float)deg + 1.0f);
        degarr[d] = deg;
        atomicAdd(&lh[63 - min(deg, 63)], 1);
    }
    __syncthreads();
    if (threadIdx.x < 64) bh[threadIdx.x * NB + blockIdx.x] = lh[threadIdx.x];
    if (blockIdx.x == 0 && threadIdx.x == 0) row_ptr[NN] = NE;
}

__global__ __launch_bounds__(1024) void permscan_kernel(int* __restrict__ bh) {
    __shared__ int wsum[16];
    const int CH = 13;  // 1024*13 = 13312 >= 12544
    int tid = threadIdx.x;
    int base = tid * CH;
    int vals[CH];
    int s = 0;
#pragma unroll
    for (int i = 0; i < CH; ++i) {
        int idx = base + i;
        int v = (idx < PH) ? bh[idx] : 0;
        vals[i] = s;
        s += v;
    }
    int lane = tid & 63, wid = tid >> 6;
    int x = s;
#pragma unroll
    for (int off = 1; off < 64; off <<= 1) {
        int t = __shfl_up(x, off, 64);
        if (lane >= off) x += t;
    }
    if (lane == 63) wsum[wid] = x;
    __syncthreads();
    if (tid == 0) {
        int run = 0;
        for (int i = 0; i < 16; ++i) { int t = wsum[i]; wsum[i] = run; run += t; }
    }
    __syncthreads();
    int texcl = x - s + wsum[wid];
#pragma unroll
    for (int i = 0; i < CH; ++i) {
        int idx = base + i;
        if (idx < PH) bh[idx] = texcl + vals[i];
    }
}

// merged: blocks [0,NB) = degree-bucket permscatter (descending degree); blocks [NB,..) =
// XCD-partitioned fill, now ATOMIC-FREE: pos = scanned_bin_base + rank[e].
__global__ void scatter_fill_kernel(const int* __restrict__ degarr, const int* __restrict__ bh,
                                    int* __restrict__ perm, const int* __restrict__ src,
                                    const int* __restrict__ dst, const int* __restrict__ excl2,
                                    const int* __restrict__ bsums, const int* __restrict__ rank,
                                    const float* __restrict__ dinv, int2* __restrict__ edge2) {
    if (blockIdx.x < NB) {
        __shared__ int lh[64];
        __shared__ int lbase[64];
        if (threadIdx.x < 64) {
            lh[threadIdx.x] = 0;
            lbase[threadIdx.x] = bh[threadIdx.x * NB + blockIdx.x];
        }
        __syncthreads();
        int gid = blockIdx.x * 256 + threadIdx.x;
        if (gid < NN) {
            int b = 63 - min(degarr[gid], 63);
            int r = atomicAdd(&lh[b], 1);
            perm[lbase[b] + r] = gid;
        }
    } else {
        int bb = blockIdx.x - NB;
        int slice = bb >> 3;
        int r = bb & 7;
        int base = slice * FS;
#pragma unroll 2
        for (int i = threadIdx.x; i < FS; i += 256) {
            int e = base + i;
            if (e < NE) {
                int d = dst[e];
                if (d / CHSZ == r) {
                    int s = src[e];
                    int bin = d * NCH + s / CHSZ;
                    int pos = excl2[bin] + bsums[bin >> 10] + rank[e];
                    int2 o;
                    o.x = s;
                    o.y = __float_as_int(dinv[s] * dinv[d]);
                    edge2[pos] = o;
                }
            }
        }
    }
}

// ---------------- fused per-layer: int8 gather-aggregate + MFMA GEMM + bias+LN+ReLU+res ----
// int8 table (128B row = 2 lines), x8 gather pipeline, descending-degree perm (LJF).
template <bool RES, bool FINAL>
__global__ __launch_bounds__(256) void layer_kernel(
    const uint2* __restrict__ qin, const float* __restrict__ scin,
    const ushort* __restrict__ fin, const int* __restrict__ row_ptr,
    const int2* __restrict__ edge2, const int* __restrict__ perm,
    const float* __restrict__ dinv, const ushort* __restrict__ Wt,
    const float* __restrict__ bias, const float* __restrict__ gamma,
    const float* __restrict__ beta, ushort* __restrict__ fout, char* __restrict__ qfout,
    float* __restrict__ scout, float* __restrict__ out) {
    __shared__ uint4 sA[16 * 17];
    __shared__ int sNode[16];
    __shared__ float sLN1[4][16], sLN2[4][16];
    __shared__ float sMX[4][16];

    int w = threadIdx.x >> 6, lane = threadIdx.x & 63;
    int g = lane >> 4, t = lane & 15;
    int arow = w * 4 + g;
    int slot = blockIdx.x * 16 + arow;  // grid 3125*16 = 50000 exact
    int node = perm[slot];
    if (t == 0) sNode[arow] = node;

    // ---- phase 1: int8 gather-aggregate (16 lanes x 8B per node row), x8 pipelined ----
    {
        int beg = row_ptr[node], end = row_ptr[node + 1];
        float acc[8] = {};
        int e = beg;
        for (; e + 8 <= end; e += 8) {
            int2 a[8];
            uint2 qv[8];
            float sc[8];
#pragma unroll
            for (int j = 0; j < 8; ++j) a[j] = edge2[e + j];
#pragma unroll
            for (int j = 0; j < 8; ++j) {
                qv[j] = qin[a[j].x * 16 + t];
                sc[j] = scin[a[j].x];
            }
#pragma unroll
            for (int j = 0; j < 8; ++j) accum_q(acc, qv[j], __int_as_float(a[j].y) * sc[j]);
        }
        for (; e + 4 <= end; e += 4) {
            int2 a[4];
            uint2 qv[4];
            float sc[4];
#pragma unroll
            for (int j = 0; j < 4; ++j) a[j] = edge2[e + j];
#pragma unroll
            for (int j = 0; j < 4; ++j) {
                qv[j] = qin[a[j].x * 16 + t];
                sc[j] = scin[a[j].x];
            }
#pragma unroll
            for (int j = 0; j < 4; ++j) accum_q(acc, qv[j], __int_as_float(a[j].y) * sc[j]);
        }
        for (; e < end; ++e) {
            int2 a = edge2[e];
            uint2 qv = qin[a.x * 16 + t];
            accum_q(acc, qv, __int_as_float(a.y) * scin[a.x]);
        }
        {
            float di = dinv[node];
            uint2 qv = qin[node * 16 + t];
            accum_q(acc, qv, di * di * scin[node]);
        }
        union { ushort us[8]; uint4 u; } pk;
#pragma unroll
        for (int i = 0; i < 8; ++i) pk.us[i] = f2bf_bits(acc[i]);
        sA[arow * 17 + t] = pk.u;
    }
    __syncthreads();

    // ---- phase 2: MFMA 16x128 tile; wave w owns col-tiles 2w, 2w+1 ----
    int q = lane >> 4, m = lane & 15;
    f32x4 c0 = (f32x4){0.f, 0.f, 0.f, 0.f};
    f32x4 c1 = (f32x4){0.f, 0.f, 0.f, 0.f};
    int n0 = 16 * (2 * w), n1 = 16 * (2 * w + 1);
#pragma unroll
    for (int kk = 0; kk < 4; ++kk) {
        bf16x8 af = *(const bf16x8*)&sA[m * 17 + kk * 4 + q];
        bf16x8 b0 = *(const bf16x8*)(Wt + (n0 + m) * DD + kk * 32 + q * 8);
        bf16x8 b1 = *(const bf16x8*)(Wt + (n1 + m) * DD + kk * 32 + q * 8);
        c0 = __builtin_amdgcn_mfma_f32_16x16x32_bf16(af, b0, c0, 0, 0, 0);
        c1 = __builtin_amdgcn_mfma_f32_16x16x32_bf16(af, b1, c1, 0, 0, 0);
    }

    // ---- epilogue: bias + LN + ReLU + residual; non-final layers also emit int8 ----
    float bb0 = bias[n0 + m], bb1 = bias[n1 + m];
    float s1[4], s2[4];
#pragma unroll
    for (int r = 0; r < 4; ++r) {
        float v0 = c0[r] + bb0, v1 = c1[r] + bb1;
        c0[r] = v0; c1[r] = v1;
        s1[r] = v0 + v1;
        s2[r] = v0 * v0 + v1 * v1;
    }
#pragma unroll
    for (int off = 1; off <= 8; off <<= 1) {
#pragma unroll
        for (int r = 0; r < 4; ++r) {
            s1[r] += __shfl_xor(s1[r], off, 64);
            s2[r] += __shfl_xor(s2[r], off, 64);
        }
    }
    if (m == 0) {
#pragma unroll
        for (int r = 0; r < 4; ++r) {
            sLN1[w][q * 4 + r] = s1[r];
            sLN2[w][q * 4 + r] = s2[r];
        }
    }
    __syncthreads();
    float ga0 = gamma[n0 + m], ga1 = gamma[n1 + m];
    float be0 = beta[n0 + m], be1 = beta[n1 + m];
    float o0v[4], o1v[4], rmax[4];
#pragma unroll
    for (int r = 0; r < 4; ++r) {
        int row = q * 4 + r;
        float S1 = sLN1[0][row] + sLN1[1][row] + sLN1[2][row] + sLN1[3][row];
        float S2 = sLN2[0][row] + sLN2[1][row] + sLN2[2][row] + sLN2[3][row];
        float mu = S1 * (1.f / 128.f);
        float var = S2 * (1.f / 128.f) - mu * mu;
        float rstd = rsqrtf(var + LN_EPS);
        int nd = sNode[row];
        size_t rb = (size_t)nd * DD;
        float o0 = fmaxf((c0[r] - mu) * rstd * ga0 + be0, 0.f);
        float o1 = fmaxf((c1[r] - mu) * rstd * ga1 + be1, 0.f);
        if (RES) {
            o0 += __uint_as_float(((uint)fin[rb + n0 + m]) << 16);
            o1 += __uint_as_float(((uint)fin[rb + n1 + m]) << 16);
        }
        if (FINAL) {
            out[rb + n0 + m] = o0;
            out[rb + n1 + m] = o1;
        } else {
            fout[rb + n0 + m] = f2bf_bits(o0);
            fout[rb + n1 + m] = f2bf_bits(o1);
            o0v[r] = o0; o1v[r] = o1;
            rmax[r] = fmaxf(o0, o1);  // o >= 0
        }
    }
    if (!FINAL) {
#pragma unroll
        for (int off = 1; off <= 8; off <<= 1) {
#pragma unroll
            for (int r = 0; r < 4; ++r) rmax[r] = fmaxf(rmax[r], __shfl_xor(rmax[r], off, 64));
        }
        if (m == 0) {
#pragma unroll
            for (int r = 0; r < 4; ++r) sMX[w][q * 4 + r] = rmax[r];
        }
        __syncthreads();
#pragma unroll
        for (int r = 0; r < 4; ++r) {
            int row = q * 4 + r;
            float M = fmaxf(fmaxf(sMX[0][row], sMX[1][row]), fmaxf(sMX[2][row], sMX[3][row]));
            float inv = 127.f / fmaxf(M, 1e-20f);
            int nd = sNode[row];
            if (w == 0 && m == 0) scout[nd] = M / 127.f;
            int q0 = min(__float2int_rn(o0v[r] * inv), 127);
            int q1 = min(__float2int_rn(o1v[r] * inv), 127);
            qfout[(size_t)nd * DD + n0 + m] = (char)q0;
            qfout[(size_t)nd * DD + n1 + m] = (char)q1;
        }
    }
}

// ---------------- launch ----------------

extern "C" void kernel_launch(void* const* d_in, const int* in_sizes, int n_in,
                              void* d_out, int out_size, void* d_ws, size_t ws_size,
                              hipStream_t stream) {
    const float* x = (const float*)d_in[0];
    const int* edge = (const int*)d_in[1];
    const float* Ws = (const float*)d_in[2];
    const float* bs = (const float*)d_in[3];
    const float* gs = (const float*)d_in[4];
    const float* bes = (const float*)d_in[5];
    float* out = (float*)d_out;
    const int* src = edge;
    const int* dst = edge + NE;

    char* p = (char*)d_ws;
    int* counts2 = (int*)p;     p += (size_t)NC2 * 4;     // scanned in place -> excl2
    int* bsums = (int*)p;       p += 1024 * 4;
    int* row_ptr = (int*)p;     p += (size_t)(NN + 4) * 4;
    int* rank = (int*)p;        p += (size_t)NE * 4;      // within-bin rank per edge
    float* dinv = (float*)p;    p += (size_t)NN * 4;
    int* degarr = (int*)p;      p += (size_t)NN * 4;
    int* bh = (int*)p;          p += (size_t)PH * 4;
    int* perm = (int*)p;        p += (size_t)NN * 4;
    int2* edge2 = (int2*)p;     p += (size_t)NE * 8;
    ushort* fb0 = (ushort*)p;   p += (size_t)NN * DD * 2;   // bf16 residual chain
    ushort* fb1 = (ushort*)p;   p += (size_t)NN * DD * 2;
    char* qf0 = (char*)p;       p += (size_t)NN * DD;       // int8 gather tables
    char* qf1 = (char*)p;       p += (size_t)NN * DD;
    float* sc0 = (float*)p;     p += (size_t)NN * 4;        // per-row scales
    float* sc1 = (float*)p;     p += (size_t)NN * 4;
    ushort* Wt = (ushort*)p;    p += (size_t)3 * DD * DD * 2;

    hipMemsetAsync(counts2, 0, (size_t)NC2 * 4, stream);
    hist_cast_kernel<<<HHB + QB + WB, 256, 0, stream>>>(src, dst, counts2, rank, x,
                                                        (uint2*)qf0, sc0, Ws, Wt);
    scan1024_blocks<<<NSB, 1024, 0, stream>>>(counts2, bsums);
    scan_sums1024<<<1, 1024, 0, stream>>>(bsums, NSB);
    finalize_kernel<<<NB, 256, 0, stream>>>(counts2, bsums, row_ptr, dinv, degarr, bh);
    permscan_kernel<<<1, 1024, 0, stream>>>(bh);
    scatter_fill_kernel<<<NB + NSL * 8, 256, 0, stream>>>(degarr, bh, perm, src, dst, counts2,
                                                          bsums, rank, dinv, edge2);

    int lg = NN / 16;  // 3125
    layer_kernel<false, false><<<lg, 256, 0, stream>>>(
        (const uint2*)qf0, sc0, fb0, row_ptr, edge2, perm, dinv, Wt, bs, gs, bes,
        fb1, qf1, sc1, out);
    layer_kernel<true, false><<<lg, 256, 0, stream>>>(
        (const uint2*)qf1, sc1, fb1, row_ptr, edge2, perm, dinv, Wt + 16384, bs + DD, gs + DD,
        bes + DD, fb0, qf0, sc0, out);
    layer_kernel<true, true><<<lg, 256, 0, stream>>>(
        (const uint2*)qf0, sc0, fb0, row_ptr, edge2, perm, dinv, Wt + 32768, bs + 2 * DD,
        gs + 2 * DD, bes + 2 * DD, fb1, qf1, sc1, out);
}